// Round 1
// baseline (588.267 us; speedup 1.0000x reference)
//
#include <hip/hip_runtime.h>
#include <math.h>

#define B_    2048
#define N_    36
#define EMB_  1024
#define SIMD_ 16
#define HID_  32
#define K_    8

// One block per batch item b. 256 threads = 4 waves.
// Phase 0: prep folded weights in LDS (Wsum = sum_k gcn_w[k], weight-normed W1/w2).
// Phase 1: each wave computes block-wise cosine sims for 9 of the 36 rows
//          (fully coalesced float4 loads, 16-lane shfl_xor reductions).
// Phase 2: wave 0, thread-per-row 16->32->tanh(32)->1 MLP, butterfly reduce,
//          out[b] = mean over rows.
// NOTE: the Gaussian-kernel graph weights row-normalize to sum S/(S+1e-8) ~= 1
// (error <= ~1.2e-8, far below the 1.55e-3 absmax threshold), and the node
// features are j-independent, so the whole pairwise-distance pipeline folds
// to identity. gk_mean/gk_prec are provably irrelevant at this tolerance.
__global__ __launch_bounds__(256) void simgsmn_kernel(
    const float* __restrict__ inp1, const float* __restrict__ inp2,
    const float* __restrict__ gcn_w,
    const float* __restrict__ out1_v, const float* __restrict__ out1_g,
    const float* __restrict__ out1_b,
    const float* __restrict__ out2_v, const float* __restrict__ out2_g,
    const float* __restrict__ out2_b,
    float* __restrict__ out)
{
    __shared__ float sSim[N_][SIMD_ + 1];   // +1 pad: kills stride-16 bank conflicts
    __shared__ float sWsum[SIMD_][HID_];
    __shared__ float sW1[HID_][HID_];
    __shared__ float sB1[HID_];
    __shared__ float sW2[HID_];

    const int tid = threadIdx.x;
    const int b   = blockIdx.x;

    // ---- Phase 0: fold weights (reads hit L2 after first blocks) ----
    for (int idx = tid; idx < SIMD_ * HID_; idx += 256) {
        float s = 0.f;
        #pragma unroll
        for (int k = 0; k < K_; ++k) s += gcn_w[k * SIMD_ * HID_ + idx];
        sWsum[idx / HID_][idx % HID_] = s;
    }
    if (tid < HID_) {
        // weight-normed out1: W1[row] = g[row] * v[row] / (||v[row]|| + 1e-12)
        float nrm = 0.f;
        #pragma unroll
        for (int h = 0; h < HID_; ++h) { float v = out1_v[tid * HID_ + h]; nrm += v * v; }
        float sc = out1_g[tid] / (sqrtf(nrm) + 1e-12f);
        #pragma unroll
        for (int h = 0; h < HID_; ++h) sW1[tid][h] = out1_v[tid * HID_ + h] * sc;
        sB1[tid] = out1_b[tid];
    } else if (tid >= 64 && tid < 64 + HID_) {
        int h = tid - 64;
        float nrm = 0.f;
        #pragma unroll
        for (int j = 0; j < HID_; ++j) { float v = out2_v[j]; nrm += v * v; }
        sW2[h] = out2_g[0] * out2_v[h] / (sqrtf(nrm) + 1e-12f);
    }
    __syncthreads();

    // ---- Phase 1: block-wise cosine sims ----
    const int wave = tid >> 6;
    const int lane = tid & 63;
    const int g    = lane >> 4;     // 16-lane group id: 0..3

    for (int i = wave; i < N_; i += 4) {             // 9 rows per wave, uniform trip count
        const float4* p1 = reinterpret_cast<const float4*>(inp1 + ((size_t)b * N_ + i) * EMB_) + lane;
        const float4* p2 = reinterpret_cast<const float4*>(inp2 + ((size_t)b * N_ + i) * EMB_) + lane;
        float qq[4], cc[4], qc[4];
        #pragma unroll
        for (int u = 0; u < 4; ++u) {
            float4 q = p1[u * 64];                   // coalesced: 16B/lane contiguous
            float4 c = p2[u * 64];
            qq[u] = q.x * q.x + q.y * q.y + q.z * q.z + q.w * q.w;
            cc[u] = c.x * c.x + c.y * c.y + c.z * c.z + c.w * c.w;
            qc[u] = q.x * c.x + q.y * c.y + q.z * c.z + q.w * c.w;
        }
        // chunk u, lane group g covers sim block s = 4u + g; reduce over the 16 lanes
        #pragma unroll
        for (int u = 0; u < 4; ++u) {
            #pragma unroll
            for (int m = 1; m < 16; m <<= 1) {
                qq[u] += __shfl_xor(qq[u], m, 64);
                cc[u] += __shfl_xor(cc[u], m, 64);
                qc[u] += __shfl_xor(qc[u], m, 64);
            }
        }
        if ((lane & 15) == 0) {
            #pragma unroll
            for (int u = 0; u < 4; ++u) {
                float sim = qc[u] / ((sqrtf(qq[u]) + 1e-8f) * (sqrtf(cc[u]) + 1e-8f));
                sSim[i][4 * u + g] = sim;
            }
        }
    }
    __syncthreads();

    // ---- Phase 2: per-row MLP + mean (wave 0 only) ----
    if (tid < 64) {
        float sv = 0.f;
        if (tid < N_) {
            const int i = tid;
            float hid[HID_];
            #pragma unroll
            for (int h = 0; h < HID_; ++h) hid[h] = 0.f;
            #pragma unroll
            for (int d = 0; d < SIMD_; ++d) {
                float s = sSim[i][d];
                #pragma unroll
                for (int h = 0; h < HID_; ++h) hid[h] += s * sWsum[d][h];  // broadcast LDS reads
            }
            float acc = out2_b[0];
            #pragma unroll
            for (int h2 = 0; h2 < HID_; ++h2) {
                float a = sB1[h2];
                #pragma unroll
                for (int h = 0; h < HID_; ++h) a += sW1[h2][h] * hid[h];   // broadcast LDS reads
                acc += sW2[h2] * tanhf(a);
            }
            sv = acc;
        }
        #pragma unroll
        for (int m = 1; m < 64; m <<= 1) sv += __shfl_xor(sv, m, 64);
        if (tid == 0) out[b] = sv * (1.f / (float)N_);
    }
}

extern "C" void kernel_launch(void* const* d_in, const int* in_sizes, int n_in,
                              void* d_out, int out_size, void* d_ws, size_t ws_size,
                              hipStream_t stream) {
    const float* inp1   = (const float*)d_in[0];
    const float* inp2   = (const float*)d_in[1];
    // d_in[2] = gk_mean, d_in[3] = gk_prec: provably irrelevant (see kernel note)
    const float* gcn_w  = (const float*)d_in[4];
    const float* out1_v = (const float*)d_in[5];
    const float* out1_g = (const float*)d_in[6];
    const float* out1_b = (const float*)d_in[7];
    const float* out2_v = (const float*)d_in[8];
    const float* out2_g = (const float*)d_in[9];
    const float* out2_b = (const float*)d_in[10];
    float* out = (float*)d_out;

    simgsmn_kernel<<<B_, 256, 0, stream>>>(inp1, inp2, gcn_w,
                                           out1_v, out1_g, out1_b,
                                           out2_v, out2_g, out2_b, out);
}